// Round 12
// baseline (714.701 us; speedup 1.0000x reference)
//
#include <hip/hip_runtime.h>
#include <math.h>

#define T_TOTAL 16384   // B*S
#define C_DIM   4096
#define E_DIM   64
#define K_TOP   8
#define S_SEQ   4096
#define B_BATCH 4
#define NKQ     8       // K splits
#define KQ_LEN  512     // channels per split
#define BK      32      // channels per LDS tile
#define NTILE   16      // KQ_LEN / BK

// ---- pack W (r9 layout): wp2[c4][j*4+eg] = float4 of W[eg*16+j][4c4..+4] ----
__global__ void pack_w_kernel(const float* __restrict__ w,
                              float4* __restrict__ wp2) {
    int g = blockIdx.x * 256 + threadIdx.x;    // [0, 1024*64)
    int c4 = g >> 6, slot = g & 63;
    int e = (slot & 3) * 16 + (slot >> 2);     // eg*16 + j
    wp2[g] = *reinterpret_cast<const float4*>(w + (size_t)e * C_DIM + c4 * 4);
}

// one pipeline stage: load W for stage SN into WN, compute stage with WC
#define WLOAD(WN, SN)                                                    \
    WN##0 = wp[(SN) * 16 + 0];  WN##1 = wp[(SN) * 16 + 4];               \
    WN##2 = wp[(SN) * 16 + 8];  WN##3 = wp[(SN) * 16 + 12];

#define COMP(WC, XA, XB, JH)                                             \
    {                                                                    \
        _Pragma("unroll")                                                \
        for (int jj = 0; jj < 4; ++jj) {                                 \
            const float4 wj = (jj == 0) ? WC##0 : (jj == 1) ? WC##1      \
                              : (jj == 2) ? WC##2 : WC##3;               \
            const int j = (JH) * 4 + jj;                                 \
            float a0 = accI[0][j], a1 = accI[1][j];                      \
            a0 = fmaf((XA).x, wj.x, a0); a0 = fmaf((XA).y, wj.y, a0);    \
            a0 = fmaf((XA).z, wj.z, a0); a0 = fmaf((XA).w, wj.w, a0);    \
            a1 = fmaf((XB).x, wj.x, a1); a1 = fmaf((XB).y, wj.y, a1);    \
            a1 = fmaf((XB).z, wj.z, a1); a1 = fmaf((XB).w, wj.w, a1);    \
            accI[0][j] = a0; accI[1][j] = a1;                            \
        }                                                                \
    }

// ---- kernel 1: partial GEMV — E_r=16, bounded W/x software pipeline ----
// grid 1024: tgb = b&127 (128-token group), kq = b>>7 (512-ch split).
// Wave wv owns tokens [tgb*128 + wv*32, +32); wave-private LDS x-tiles, NO
// barriers. lane = (tl = lane&15 token-lane, eg = lane>>4 expert-group);
// lane computes 2 tokens x 16 experts. Per 64-cyc stage: 4 W float4 loads
// into the idle one of {wA,wB} (WAR-bounded in flight) + 32 fma from the
// other. x ds_reads prefetched one c4 ahead (xv/xn alternating). Numerics:
// ascending channels, xyzw order, 256-ch flush — bit-identical to r9.
__global__ __launch_bounds__(256, 4)
void gemv_kernel(const float* __restrict__ x,
                 const float4* __restrict__ wp2,
                 float* __restrict__ part) {
    const int tid  = threadIdx.x;
    const int lane = tid & 63;
    const int wv   = tid >> 6;
    const int tl   = lane & 15;
    const int eg   = lane >> 4;
    const int tgb  = blockIdx.x & 127;
    const int kq   = blockIdx.x >> 7;
    const int wtok0 = tgb * 128 + wv * 32;       // wave's 32 tokens

    // r9's measured-conflict-free layout: 32 rows x 9 float4 (pad), dbuf
    __shared__ float4 xs[4][2][32][9];           // 36864 B

    // r9 staging map: lane -> rows {row8, +8, +16, +24}, slot ss
    const int row8 = lane >> 3;                  // 0..7
    const int ss   = lane & 7;                   // 0..7
    const float* xsrc = x + (size_t)(wtok0 + row8) * C_DIM + kq * KQ_LEN + ss * 4;

    float4 xf0, xf1, xf2, xf3;
    xf0 = *reinterpret_cast<const float4*>(xsrc);
    xf1 = *reinterpret_cast<const float4*>(xsrc + 8 * C_DIM);
    xf2 = *reinterpret_cast<const float4*>(xsrc + 16 * C_DIM);
    xf3 = *reinterpret_cast<const float4*>(xsrc + 24 * C_DIM);
    xs[wv][0][row8][ss]      = xf0;
    xs[wv][0][row8 + 8][ss]  = xf1;
    xs[wv][0][row8 + 16][ss] = xf2;
    xs[wv][0][row8 + 24][ss] = xf3;

    float accI[2][16], accO[2][16];
#pragma unroll
    for (int j = 0; j < 16; ++j) {
        accI[0][j] = 0.0f; accI[1][j] = 0.0f;
        accO[0][j] = 0.0f; accO[1][j] = 0.0f;
    }

    const float4* wkq = wp2 + ((size_t)kq << 13) + eg;   // kq*8192 + eg

    float4 wA0, wA1, wA2, wA3, wB0, wB1, wB2, wB3;
    {   // prologue: preload tile-0 stage-0 W
        const float4* wp = wkq;
        WLOAD(wA, 0)
    }

#pragma unroll 1
    for (int t = 0; t < NTILE; ++t) {
        const int cur = t & 1;
        if (t + 1 < NTILE) {                     // global prefetch next x tile
            const float* xn = xsrc + (t + 1) * BK;
            xf0 = *reinterpret_cast<const float4*>(xn);
            xf1 = *reinterpret_cast<const float4*>(xn + 8 * C_DIM);
            xf2 = *reinterpret_cast<const float4*>(xn + 16 * C_DIM);
            xf3 = *reinterpret_cast<const float4*>(xn + 24 * C_DIM);
        }

        const float4* wp = wkq + t * 512;        // linear stage addressing
        float4 xv0 = xs[wv][cur][tl][0];
        float4 xv1 = xs[wv][cur][tl + 16][0];
        float4 xn0, xn1;

#pragma unroll 1
        for (int c4 = 0; c4 < 8; c4 += 2) {
            const int s0 = c4 * 4;
            // prefetch x for c4+1
            xn0 = xs[wv][cur][tl][c4 + 1];
            xn1 = xs[wv][cur][tl + 16][c4 + 1];
            // stages s0..s0+3 (even c4): consume xv, alternate wA/wB
            WLOAD(wB, s0 + 1) COMP(wA, xv0, xv1, 0)
            WLOAD(wA, s0 + 2) COMP(wB, xv0, xv1, 1)
            WLOAD(wB, s0 + 3) COMP(wA, xv0, xv1, 2)
            WLOAD(wA, s0 + 4) COMP(wB, xv0, xv1, 3)
            // prefetch x for c4+2 (next even c4)
            if (c4 + 2 < 8) {
                xv0 = xs[wv][cur][tl][c4 + 2];
                xv1 = xs[wv][cur][tl + 16][c4 + 2];
            }
            // stages s0+4..s0+7 (odd c4): consume xn
            WLOAD(wB, s0 + 5) COMP(wA, xn0, xn1, 0)
            WLOAD(wA, s0 + 6) COMP(wB, xn0, xn1, 1)
            WLOAD(wB, s0 + 7) COMP(wA, xn0, xn1, 2)
            WLOAD(wA, s0 + 8) COMP(wB, xn0, xn1, 3)
            // s0+8 at c4==6 -> (t+1)*512 slot 0: rolls into next tile's wA.
            // At t==15 it reads past wp2 into the part region (allocated, unused).
        }

        if ((t & 7) == 7) {                      // flush every 256 channels
#pragma unroll
            for (int j = 0; j < 16; ++j) {
                accO[0][j] += accI[0][j]; accI[0][j] = 0.0f;
                accO[1][j] += accI[1][j]; accI[1][j] = 0.0f;
            }
        }

        if (t + 1 < NTILE) {                     // commit prefetch to other buf
            const int nxt = cur ^ 1;
            xs[wv][nxt][row8][ss]      = xf0;
            xs[wv][nxt][row8 + 8][ss]  = xf1;
            xs[wv][nxt][row8 + 16][ss] = xf2;
            xs[wv][nxt][row8 + 24][ss] = xf3;
        }
        // NO barrier: tiles are wave-private
    }

    // store partials: part[kq][tok][e]; 16 consecutive experts per lane
#pragma unroll
    for (int r = 0; r < 2; ++r) {
        float* pb = part + ((size_t)kq * T_TOTAL + wtok0 + tl + 16 * r)
                            * E_DIM + eg * 16;
#pragma unroll
        for (int q = 0; q < 4; ++q)
            *reinterpret_cast<float4*>(pb + 4 * q) =
                make_float4(accO[r][4 * q], accO[r][4 * q + 1],
                            accO[r][4 * q + 2], accO[r][4 * q + 3]);
    }
}

// ---- kernel 2: reduce 8 splits + sigmoid + top-8 + f/p partials ----
__global__ __launch_bounds__(256, 4)
void topk_kernel(const float* __restrict__ part,
                 const float* __restrict__ expert_bias,
                 float* __restrict__ out,
                 float* __restrict__ facc,
                 float* __restrict__ pacc) {
    const int lane = threadIdx.x & 63;
    const int wv   = threadIdx.x >> 6;
    const int tok0 = blockIdx.x * 64;

    __shared__ float slog[64][65];

    const int tt  = lane >> 2;
    const int s   = lane & 3;
    const int tl  = wv * 16 + tt;          // token-in-block
    const int tok = tok0 + tl;

    float4 sum4[4];
#pragma unroll
    for (int i = 0; i < 4; ++i) sum4[i] = make_float4(0.f, 0.f, 0.f, 0.f);
#pragma unroll
    for (int kq = 0; kq < NKQ; ++kq) {     // serial split sum (deterministic)
        const float4* pp = reinterpret_cast<const float4*>(
            part + ((size_t)kq * T_TOTAL + tok) * E_DIM + 16 * s);
#pragma unroll
        for (int i = 0; i < 4; ++i) {
            float4 v = pp[i];
            sum4[i].x += v.x; sum4[i].y += v.y;
            sum4[i].z += v.z; sum4[i].w += v.w;
        }
    }
#pragma unroll
    for (int i = 0; i < 4; ++i) {
        slog[tl][16 * s + 4 * i + 0] = sum4[i].x;
        slog[tl][16 * s + 4 * i + 1] = sum4[i].y;
        slog[tl][16 * s + 4 * i + 2] = sum4[i].z;
        slog[tl][16 * s + 4 * i + 3] = sum4[i].w;
    }
    __syncthreads();

    // ---- phase B: lane = expert; wave wv handles tokens wv*16 .. wv*16+15
    const float be = expert_bias[lane];
    const int   b  = tok0 / S_SEQ;         // uniform per block
    float f_local = 0.0f, p_local = 0.0f;

    for (int m = 0; m < 16; ++m) {
        const int tl2 = wv * 16 + m;
        const int tk  = tok0 + tl2;
        const float logit = slog[tl2][lane];
        const float sc = 1.0f / (1.0f + expf(-logit));   // sigmoid
        float ssum = sc;
#pragma unroll
        for (int off = 32; off >= 1; off >>= 1) ssum += __shfl_xor(ssum, off, 64);
        p_local += sc / (ssum + 1e-10f);

        // top-8 over biased logits (descending, lowest-index tie-break)
        float v = logit + be;
        float wsum = 0.0f, my_w = 0.0f;
        int   my_i = 0;
#pragma unroll
        for (int k = 0; k < K_TOP; ++k) {
            float rv = v;
            int   ri = lane;
#pragma unroll
            for (int off = 32; off >= 1; off >>= 1) {
                float ov = __shfl_xor(rv, off, 64);
                int   oi = __shfl_xor(ri, off, 64);
                if (ov > rv || (ov == rv && oi < ri)) { rv = ov; ri = oi; }
            }
            float wsc = __shfl(sc, ri, 64);   // winner's score (uniform)
            wsum += wsc;
            if (lane == k)  { my_i = ri; my_w = wsc; }
            if (lane == ri) { v = -INFINITY; f_local += 1.0f; }
        }
        if (lane < K_TOP) {
            out[(size_t)tk * K_TOP + lane] = (float)my_i;
            out[(size_t)T_TOTAL * K_TOP + (size_t)tk * K_TOP + lane] =
                my_w / (wsum + 1e-10f);
        }
    }

    atomicAdd(&facc[b * E_DIM + lane], f_local);
    atomicAdd(&pacc[b * E_DIM + lane], p_local);
}

// ---- tiny loss reduction: 4x64 f*p -> scalar ----
__global__ void loss_kernel(const float* __restrict__ facc,
                            const float* __restrict__ pacc,
                            float* __restrict__ out_loss) {
    const int tid = threadIdx.x;                 // 256 threads = B*E
    float f = facc[tid] * (1.0f / ((float)K_TOP * (float)S_SEQ));
    float p = pacc[tid] * (1.0f / (float)S_SEQ);
    float v = f * p;
#pragma unroll
    for (int off = 32; off >= 1; off >>= 1) v += __shfl_xor(v, off, 64);
    __shared__ float sred[4];
    if ((tid & 63) == 0) sred[tid >> 6] = v;
    __syncthreads();
    if (tid == 0) {
        float tot = sred[0] + sred[1] + sred[2] + sred[3];
        out_loss[0] = 0.001f * tot / (float)B_BATCH;
    }
}

extern "C" void kernel_launch(void* const* d_in, const int* in_sizes, int n_in,
                              void* d_out, int out_size, void* d_ws, size_t ws_size,
                              hipStream_t stream) {
    const float* x    = (const float*)d_in[0];   // [4,4096,4096] f32
    const float* w    = (const float*)d_in[1];   // [64,4096] f32
    const float* bias = (const float*)d_in[2];   // [64] f32
    float* out = (float*)d_out;                  // [131072 idx][131072 w][1 loss]

    float*  facc = (float*)d_ws;                 // 256 floats
    float*  pacc = facc + B_BATCH * E_DIM;       // 256 floats
    float4* wp2  = (float4*)((char*)d_ws + 4096);              // 1 MB packed W
    float*  part = (float*)((char*)d_ws + 4096 + (1 << 20));   // 32 MB partials

    // zero the f/p accumulators every call (atomics accumulate)
    hipMemsetAsync(d_ws, 0, 2048, stream);

    pack_w_kernel<<<256, 256, 0, stream>>>(w, wp2);

    gemv_kernel<<<128 * NKQ, 256, 0, stream>>>(x, wp2, part);

    topk_kernel<<<T_TOTAL / 64, 256, 0, stream>>>(part, bias, out, facc, pacc);

    loss_kernel<<<1, 256, 0, stream>>>(facc, pacc, out + 2 * (size_t)T_TOTAL * K_TOP);
}

// Round 13
// 151.446 us; speedup vs baseline: 4.7192x; 4.7192x over previous
//
#include <hip/hip_runtime.h>
#include <math.h>

#define T_TOTAL 16384   // B*S
#define C_DIM   4096
#define E_DIM   64
#define K_TOP   8
#define S_SEQ   4096
#define B_BATCH 4

typedef short  short8 __attribute__((ext_vector_type(8)));
typedef float  f32x4  __attribute__((ext_vector_type(4)));

__device__ __forceinline__ unsigned short bf16_rte(float x) {
    unsigned u = __float_as_uint(x);
    return (unsigned short)((u + 0x7fffu + ((u >> 16) & 1u)) >> 16);
}
__device__ __forceinline__ float bf16_back(unsigned short h) {
    return __uint_as_float(((unsigned)h) << 16);
}

// ---- pack W into B-fragment layout, 3 bf16 split planes ----
// wb[((s*128 + kt)*4 + n)*64 + l] = uint4 of 8 bf16:
//   elem i = split_s( W[n*16 + (l&15)][kt*32 + (l>>4)*8 + i] )
// (k-map (l>>4)*8+i is chosen; correctness needs only A/B consistency.)
__global__ void pack_w_kernel(const float* __restrict__ w,
                              uint4* __restrict__ wb) {
    int gidx = blockIdx.x * 256 + threadIdx.x;   // [0, 98304)
    int l  = gidx & 63;
    int n  = (gidx >> 6) & 3;
    int kt = (gidx >> 8) & 127;
    int s  = gidx >> 15;                         // 0..2
    int e  = n * 16 + (l & 15);
    int kb = kt * 32 + (l >> 4) * 8;
    const float* src = w + (size_t)e * C_DIM + kb;
    unsigned short h[8];
#pragma unroll
    for (int i = 0; i < 8; ++i) {
        float v = src[i];
        unsigned short b1 = bf16_rte(v);
        if (s == 0) { h[i] = b1; continue; }
        float r = v - bf16_back(b1);             // exact (Sterbenz)
        unsigned short b2 = bf16_rte(r);
        if (s == 1) { h[i] = b2; continue; }
        float r2 = r - bf16_back(b2);            // exact
        h[i] = bf16_rte(r2);
    }
    uint4 o;
    o.x = (unsigned)h[0] | ((unsigned)h[1] << 16);
    o.y = (unsigned)h[2] | ((unsigned)h[3] << 16);
    o.z = (unsigned)h[4] | ((unsigned)h[5] << 16);
    o.w = (unsigned)h[6] | ((unsigned)h[7] << 16);
    wb[gidx] = o;
}

// one K=32 step: split x to 3 bf16 A-frags, 12 B-frag loads, 24 MFMAs
__device__ __forceinline__ void kstep(const uint4* __restrict__ wstep,
                                      const float xv[8], f32x4 accI[4]) {
    short8 A1, A2, A3;
#pragma unroll
    for (int i = 0; i < 8; ++i) {
        float v = xv[i];
        unsigned short h1 = bf16_rte(v);
        float r = v - bf16_back(h1);
        unsigned short h2 = bf16_rte(r);
        float r2 = r - bf16_back(h2);
        unsigned short h3 = bf16_rte(r2);
        A1[i] = (short)h1; A2[i] = (short)h2; A3[i] = (short)h3;
    }
    uint4 q[3][4];
#pragma unroll
    for (int s = 0; s < 3; ++s)
#pragma unroll
        for (int n = 0; n < 4; ++n)
            q[s][n] = wstep[s * 32768 + n * 64];
    union { uint4 u; short8 v; } cv;
#pragma unroll
    for (int n = 0; n < 4; ++n) {
        short8 B1, B2, B3;
        cv.u = q[0][n]; B1 = cv.v;
        cv.u = q[1][n]; B2 = cv.v;
        cv.u = q[2][n]; B3 = cv.v;
        f32x4 c = accI[n];
        c = __builtin_amdgcn_mfma_f32_16x16x32_bf16(A1, B1, c, 0, 0, 0);
        c = __builtin_amdgcn_mfma_f32_16x16x32_bf16(A1, B2, c, 0, 0, 0);
        c = __builtin_amdgcn_mfma_f32_16x16x32_bf16(A2, B1, c, 0, 0, 0);
        c = __builtin_amdgcn_mfma_f32_16x16x32_bf16(A1, B3, c, 0, 0, 0);
        c = __builtin_amdgcn_mfma_f32_16x16x32_bf16(A3, B1, c, 0, 0, 0);
        c = __builtin_amdgcn_mfma_f32_16x16x32_bf16(A2, B2, c, 0, 0, 0);
        accI[n] = c;
    }
}

// ---- fused gate: bf16x3 MFMA GEMM + verified top-8 epilogue ----
// 256 blocks x 512 threads. Block = 64 tokens. Wave wv: M-tile mt = wv&3
// (16 tokens), K-half kh = wv>>2 (2048 ch). No LDS / barriers in main loop.
// A-frag: row = lane&15 (token), k = (lane>>4)*8+i -> 2 coalesced float4
// per step, 2-deep named prefetch (no runtime-indexed arrays).
// Chunked flush every 8 steps (256 ch) mirrors the verified numerics.
__global__ __launch_bounds__(512, 2)
void gate_mfma_kernel(const float* __restrict__ x,
                      const uint4* __restrict__ wb,
                      const float* __restrict__ expert_bias,
                      float* __restrict__ out,
                      float* __restrict__ facc,
                      float* __restrict__ pacc) {
    const int tid  = threadIdx.x;
    const int lane = tid & 63;
    const int wv   = tid >> 6;        // 0..7
    const int mt   = wv & 3;
    const int kh   = wv >> 2;
    const int tok0 = blockIdx.x * 64;
    const int row  = lane & 15;
    const int g    = lane >> 4;

    __shared__ float slog[2][64][65];

    const float* xptr = x + (size_t)(tok0 + mt * 16 + row) * C_DIM
                          + kh * 2048 + g * 8;
    const uint4* wbl  = wb + lane + (size_t)(kh * 64) * 256;  // + t*256

    f32x4 accI[4], accO[4];
#pragma unroll
    for (int n = 0; n < 4; ++n)
#pragma unroll
        for (int j = 0; j < 4; ++j) { accI[n][j] = 0.0f; accO[n][j] = 0.0f; }

    // 2-deep x prefetch, named regs (even/odd)
    float4 ea0 = *(const float4*)(xptr);
    float4 ea1 = *(const float4*)(xptr + 4);
    float4 ob0 = *(const float4*)(xptr + 32);
    float4 ob1 = *(const float4*)(xptr + 36);

#pragma unroll 1
    for (int t = 0; t < 64; t += 2) {
        float xe[8] = {ea0.x, ea0.y, ea0.z, ea0.w, ea1.x, ea1.y, ea1.z, ea1.w};
        if (t + 2 < 64) {
            ea0 = *(const float4*)(xptr + (t + 2) * 32);
            ea1 = *(const float4*)(xptr + (t + 2) * 32 + 4);
        }
        kstep(wbl + (size_t)t * 256, xe, accI);

        float xo[8] = {ob0.x, ob0.y, ob0.z, ob0.w, ob1.x, ob1.y, ob1.z, ob1.w};
        if (t + 3 < 64) {
            ob0 = *(const float4*)(xptr + (t + 3) * 32);
            ob1 = *(const float4*)(xptr + (t + 3) * 32 + 4);
        }
        kstep(wbl + (size_t)(t + 1) * 256, xo, accI);

        if ((t & 7) == 6) {                      // flush every 8 steps = 256 ch
#pragma unroll
            for (int n = 0; n < 4; ++n)
#pragma unroll
                for (int j = 0; j < 4; ++j) {
                    accO[n][j] += accI[n][j]; accI[n][j] = 0.0f;
                }
        }
    }

    // write logits: C/D verified map: col = lane&15 (expert), row = g*4+r (token)
#pragma unroll
    for (int n = 0; n < 4; ++n)
#pragma unroll
        for (int r = 0; r < 4; ++r)
            slog[kh][mt * 16 + g * 4 + r][n * 16 + row] = accO[n][r];
    __syncthreads();

    // ---- phase 2: verified top-8 butterfly; wave wv handles 8 tokens ----
    const float be = expert_bias[lane];
    const int   b  = tok0 / S_SEQ;               // uniform per block
    float f_local = 0.0f, p_local = 0.0f;

    for (int m = 0; m < 8; ++m) {
        const int tl = wv * 8 + m;
        const int tk = tok0 + tl;
        const float logit = slog[0][tl][lane] + slog[1][tl][lane];
        const float sc = 1.0f / (1.0f + expf(-logit));   // sigmoid
        float ssum = sc;
#pragma unroll
        for (int off = 32; off >= 1; off >>= 1) ssum += __shfl_xor(ssum, off, 64);
        p_local += sc / (ssum + 1e-10f);

        float v = logit + be;
        float wsum = 0.0f, my_w = 0.0f;
        int   my_i = 0;
#pragma unroll
        for (int k = 0; k < K_TOP; ++k) {
            float rv = v;
            int   ri = lane;
#pragma unroll
            for (int off = 32; off >= 1; off >>= 1) {
                float ov = __shfl_xor(rv, off, 64);
                int   oi = __shfl_xor(ri, off, 64);
                if (ov > rv || (ov == rv && oi < ri)) { rv = ov; ri = oi; }
            }
            float wsc = __shfl(sc, ri, 64);      // winner's score (uniform)
            wsum += wsc;
            if (lane == k)  { my_i = ri; my_w = wsc; }
            if (lane == ri) { v = -INFINITY; f_local += 1.0f; }
        }
        if (lane < K_TOP) {
            out[(size_t)tk * K_TOP + lane] = (float)my_i;
            out[(size_t)T_TOTAL * K_TOP + (size_t)tk * K_TOP + lane] =
                my_w / (wsum + 1e-10f);
        }
    }

    atomicAdd(&facc[b * E_DIM + lane], f_local);
    atomicAdd(&pacc[b * E_DIM + lane], p_local);
}

// ---- tiny loss reduction: 4x64 f*p -> scalar ----
__global__ void loss_kernel(const float* __restrict__ facc,
                            const float* __restrict__ pacc,
                            float* __restrict__ out_loss) {
    const int tid = threadIdx.x;                 // 256 threads = B*E
    float f = facc[tid] * (1.0f / ((float)K_TOP * (float)S_SEQ));
    float p = pacc[tid] * (1.0f / (float)S_SEQ);
    float v = f * p;
#pragma unroll
    for (int off = 32; off >= 1; off >>= 1) v += __shfl_xor(v, off, 64);
    __shared__ float sred[4];
    if ((tid & 63) == 0) sred[tid >> 6] = v;
    __syncthreads();
    if (tid == 0) {
        float tot = sred[0] + sred[1] + sred[2] + sred[3];
        out_loss[0] = 0.001f * tot / (float)B_BATCH;
    }
}

extern "C" void kernel_launch(void* const* d_in, const int* in_sizes, int n_in,
                              void* d_out, int out_size, void* d_ws, size_t ws_size,
                              hipStream_t stream) {
    const float* x    = (const float*)d_in[0];   // [4,4096,4096] f32
    const float* w    = (const float*)d_in[1];   // [64,4096] f32
    const float* bias = (const float*)d_in[2];   // [64] f32
    float* out = (float*)d_out;                  // [131072 idx][131072 w][1 loss]

    float* facc = (float*)d_ws;                  // 256 floats
    float* pacc = facc + B_BATCH * E_DIM;        // 256 floats
    uint4* wb   = (uint4*)((char*)d_ws + 4096);  // 1.5 MB packed split-W

    // zero the f/p accumulators every call (atomics accumulate)
    hipMemsetAsync(d_ws, 0, 2048, stream);

    pack_w_kernel<<<384, 256, 0, stream>>>(w, wb);

    gate_mfma_kernel<<<256, 512, 0, stream>>>(x, wb, bias, out, facc, pacc);

    loss_kernel<<<1, 256, 0, stream>>>(facc, pacc, out + 2 * (size_t)T_TOTAL * K_TOP);
}